// Round 5
// baseline (47.732 us; speedup 1.0000x reference)
//
#include <hip/hip_runtime.h>
#include <hip/hip_bf16.h>
#include <math.h>

#define BB 2
#define CC 32
#define C8 4
#define NN 4096
#define JG 8          // j-split groups
#define JR (NN/JG)    // 512 keys per block
#define LOG2E 1.4426950408889634f

typedef __attribute__((ext_vector_type(8))) short short8;
typedef __attribute__((ext_vector_type(4))) float f32x4;
typedef __attribute__((ext_vector_type(4))) unsigned int u32x4;

static __device__ __forceinline__ short f2bf(float x) {
    return __builtin_bit_cast(short, __float2bfloat16(x));
}
// round-half-up bf16 pair pack: {bf16(b), bf16(a)} -> uint (a in low half)
static __device__ __forceinline__ unsigned int pkbf(float a, float b) {
    unsigned int ua = __builtin_bit_cast(unsigned int, a) + 0x8000u;
    unsigned int ub = __builtin_bit_cast(unsigned int, b) + 0x8000u;
    return (ua >> 16) | (ub & 0xffff0000u);
}

// ---------------- K1: QKV projection (blocks 0..31) + CAM gram, c<=d (blocks 32..295) ----
__global__ __launch_bounds__(256) void k1(const float* __restrict__ x,
    const float* __restrict__ wq, const float* __restrict__ bq,
    const float* __restrict__ wk, const float* __restrict__ bk,
    const float* __restrict__ wv, const float* __restrict__ bv,
    float* __restrict__ q, float* __restrict__ k, short* __restrict__ vbf,
    float* __restrict__ eng)
{
    if (blockIdx.x >= 32) {
        // ---- keng: one wave per unordered pair (c<=d); 528 pairs per batch ----
        int w = threadIdx.x >> 6, lane = threadIdx.x & 63;
        int pp = (blockIdx.x - 32)*4 + w;     // 0..1055
        int b = pp >= 528 ? 1 : 0;
        int t = pp - b*528;
        int c = 0, rem = t;
        while (rem >= CC - c) { rem -= CC - c; ++c; }
        int d = c + rem;
        const float4* xc = (const float4*)(x + ((size_t)b*CC + c)*NN);
        const float4* xd = (const float4*)(x + ((size_t)b*CC + d)*NN);
        float s = 0.f;
        for (int tt = lane; tt < NN/4; tt += 64) {
            float4 a = xc[tt], bb = xd[tt];
            s += a.x*bb.x + a.y*bb.y + a.z*bb.z + a.w*bb.w;
        }
        #pragma unroll
        for (int off = 32; off; off >>= 1) s += __shfl_down(s, off, 64);
        if (lane == 0) {
            eng[(b*CC + c)*CC + d] = s;
            eng[(b*CC + d)*CC + c] = s;
        }
        return;
    }
    // ---- kproj: thread = (b,n) ----
    __shared__ float swq[C8*CC], swk[C8*CC], swv[CC*CC], sbq[C8], sbk[C8], sbv[CC];
    int tid = threadIdx.x;
    for (int i = tid; i < C8*CC; i += 256) { swq[i] = wq[i]; swk[i] = wk[i]; }
    for (int i = tid; i < CC*CC; i += 256) swv[i] = wv[i];
    if (tid < C8) { sbq[tid] = bq[tid]; sbk[tid] = bk[tid]; }
    if (tid < CC) sbv[tid] = bv[tid];
    __syncthreads();
    int g = blockIdx.x*256 + tid;         // 0..8191
    int b = g >> 12; int n = g & (NN-1);
    const float* xb = x + (size_t)b*CC*NN + n;
    float xr[CC];
    #pragma unroll
    for (int c = 0; c < CC; ++c) xr[c] = xb[(size_t)c*NN];
    #pragma unroll
    for (int o = 0; o < C8; ++o) {
        float aq = sbq[o], ak = sbk[o];
        #pragma unroll
        for (int c = 0; c < CC; ++c) { aq += swq[o*CC+c]*xr[c]; ak += swk[o*CC+c]*xr[c]; }
        q[((size_t)b*C8+o)*NN + n] = aq;
        k[((size_t)b*C8+o)*NN + n] = ak;
    }
    #pragma unroll
    for (int o = 0; o < CC; ++o) {
        float av = sbv[o];
        #pragma unroll
        for (int c = 0; c < CC; ++c) av += swv[o*CC+c]*xr[c];
        vbf[((size_t)b*CC+o)*NN + n] = f2bf(av);
    }
}

// ---------------- K2: flash PAM (blocks 0..511) + Wx fold (blocks 512..513) ----
// Block = 128 queries x 512-key slab. 4 waves; wave = 32 queries (two 16-col
// MFMA B-subtiles sharing all K ds_reads and V loads). K slab in LDS (8 KB).
__global__ __launch_bounds__(256, 2) void k2(const float* __restrict__ qg,
    const float* __restrict__ kg, const short* __restrict__ vbf,
    float* __restrict__ part,
    const float* __restrict__ eng, const float* __restrict__ wo,
    const float* __restrict__ gc, float* __restrict__ wx)
{
    if (blockIdx.x >= BB*32*JG) {
        // ---- kwx: softmax(cattn) folded into Wx, one block per batch ----
        __shared__ float se_[CC*CC], sc[CC*CC];
        int b = blockIdx.x - BB*32*JG, tid = threadIdx.x;
        for (int i = tid; i < CC*CC; i += 256) se_[i] = eng[b*CC*CC + i];
        __syncthreads();
        if (tid < CC) {
            float mn = se_[tid*CC];
            #pragma unroll
            for (int d = 1; d < CC; ++d) mn = fminf(mn, se_[tid*CC+d]);
            float pv[CC]; float s = 0.f;
            #pragma unroll
            for (int d = 0; d < CC; ++d) { pv[d] = __expf(mn - se_[tid*CC+d]); s += pv[d]; }
            float inv = 1.f/s;
            #pragma unroll
            for (int d = 0; d < CC; ++d) sc[tid*CC+d] = pv[d]*inv;
        }
        __syncthreads();
        float g = gc[0];
        for (int i = tid; i < CC*CC; i += 256) {
            int o = i >> 5, d = i & 31;
            float acc = wo[o*64 + d] + wo[o*64 + 32 + d];
            float t = 0.f;
            #pragma unroll
            for (int c2 = 0; c2 < CC; ++c2) t += wo[o*64 + 32 + c2] * sc[c2*CC + d];
            wx[b*CC*CC + i] = acc + g * t;
        }
        return;
    }

    __shared__ alignas(16) float kl[4*JR];     // 8 KB K slab [d][JR]

    int blk = blockIdx.x;
    int b = blk >> 8;            // 256 blocks per batch
    int r = blk & 255;
    int it = r >> 3;             // 0..31 i-tile (128 queries)
    int jg = r & (JG-1);         // 0..7

    const float* kb = kg + (size_t)b*C8*NN + jg*JR;
    {   // cooperative K staging: 512 float4
        float4* kl4 = (float4*)kl;
        int tid = threadIdx.x;
        #pragma unroll
        for (int rr = 0; rr < 2; ++rr) {
            int idx = tid + rr*256;          // 0..511
            int d = idx >> 7;                // [d][128 float4]
            int c4 = idx & 127;
            kl4[idx] = *(const float4*)(kb + (size_t)d*NN + c4*4);
        }
    }
    __syncthreads();

    int w = threadIdx.x >> 6, lane = threadIdx.x & 63;
    int il = lane & 15;          // query column within subtile
    int g  = lane >> 4;          // k-group 0..3
    int i0 = it*128 + w*32;

    const float* qb = qg + (size_t)b*C8*NN;
    float qrA[4], qrB[4];
    #pragma unroll
    for (int d = 0; d < 4; ++d) {
        qrA[d] = qb[(size_t)d*NN + i0 + il] * LOG2E;
        qrB[d] = qb[(size_t)d*NN + i0 + 16 + il] * LOG2E;
    }

    const short* vb  = vbf + (size_t)b*CC*NN + jg*JR;
    const short* va0 = vb + (size_t)il*NN;        // A row c = il
    const short* va1 = vb + (size_t)(16+il)*NN;   // A row c = 16+il
    int lc = g*8;                                  // lane col base within slab

    f32x4 accA0 = {0.f,0.f,0.f,0.f};
    f32x4 accA1 = {0.f,0.f,0.f,0.f};
    f32x4 accB0 = {0.f,0.f,0.f,0.f};
    f32x4 accB1 = {0.f,0.f,0.f,0.f};
    float seA = 0.f, seB = 0.f;

    // depth-2 prefetch ring for V (overrun reads stay inside workspace)
    short8 cur0 = *(const short8*)(va0 + lc);
    short8 cur1 = *(const short8*)(va1 + lc);
    short8 nxt0 = *(const short8*)(va0 + lc + 32);
    short8 nxt1 = *(const short8*)(va1 + lc + 32);

    #pragma unroll 4
    for (int t = 0; t < JR/32; ++t) {
        short8 pf0 = *(const short8*)(va0 + lc + (t+2)*32);
        short8 pf1 = *(const short8*)(va1 + lc + (t+2)*32);
        int kc = lc + t*32;
        float eA[8], eB[8];
        #pragma unroll
        for (int tt = 0; tt < 8; ++tt) { eA[tt] = 0.f; eB[tt] = 0.f; }
        #pragma unroll
        for (int d = 0; d < 4; ++d) {
            float4 kA = *(const float4*)(kl + d*JR + kc);
            float4 kB = *(const float4*)(kl + d*JR + kc + 4);
            float qa = qrA[d], qbv = qrB[d];
            eA[0] += qa*kA.x; eA[1] += qa*kA.y; eA[2] += qa*kA.z; eA[3] += qa*kA.w;
            eA[4] += qa*kB.x; eA[5] += qa*kB.y; eA[6] += qa*kB.z; eA[7] += qa*kB.w;
            eB[0] += qbv*kA.x; eB[1] += qbv*kA.y; eB[2] += qbv*kA.z; eB[3] += qbv*kA.w;
            eB[4] += qbv*kB.x; eB[5] += qbv*kB.y; eB[6] += qbv*kB.z; eB[7] += qbv*kB.w;
        }
        float pA[8], pB[8];
        #pragma unroll
        for (int tt = 0; tt < 8; ++tt) { pA[tt] = exp2f(eA[tt]); pB[tt] = exp2f(eB[tt]); }
        seA += ((pA[0]+pA[1])+(pA[2]+pA[3])) + ((pA[4]+pA[5])+(pA[6]+pA[7]));
        seB += ((pB[0]+pB[1])+(pB[2]+pB[3])) + ((pB[4]+pB[5])+(pB[6]+pB[7]));
        u32x4 wA, wB;
        wA[0] = pkbf(pA[0], pA[1]); wA[1] = pkbf(pA[2], pA[3]);
        wA[2] = pkbf(pA[4], pA[5]); wA[3] = pkbf(pA[6], pA[7]);
        wB[0] = pkbf(pB[0], pB[1]); wB[1] = pkbf(pB[2], pB[3]);
        wB[2] = pkbf(pB[4], pB[5]); wB[3] = pkbf(pB[6], pB[7]);
        short8 bpA = __builtin_bit_cast(short8, wA);
        short8 bpB = __builtin_bit_cast(short8, wB);
        accA0 = __builtin_amdgcn_mfma_f32_16x16x32_bf16(cur0, bpA, accA0, 0, 0, 0);
        accA1 = __builtin_amdgcn_mfma_f32_16x16x32_bf16(cur1, bpA, accA1, 0, 0, 0);
        accB0 = __builtin_amdgcn_mfma_f32_16x16x32_bf16(cur0, bpB, accB0, 0, 0, 0);
        accB1 = __builtin_amdgcn_mfma_f32_16x16x32_bf16(cur1, bpB, accB1, 0, 0, 0);
        cur0 = nxt0; cur1 = nxt1;
        nxt0 = pf0;  nxt1 = pf1;
    }

    // reduce sumexp across the 4 k-groups (lanes with same il)
    seA += __shfl_xor(seA, 16, 64);
    seA += __shfl_xor(seA, 32, 64);
    seB += __shfl_xor(seB, 16, 64);
    seB += __shfl_xor(seB, 32, 64);

    // partials: part[b][jg][f][n], f=0..31 = channel c (unnormalized PV), f=32 = sumexp
    float* pb  = part + ((size_t)(b*JG + jg)*33)*NN + i0 + il;
    float* pbB = pb + 16;
    #pragma unroll
    for (int rr = 0; rr < 4; ++rr) {
        pb [(size_t)(g*4 + rr)*NN]      = accA0[rr];
        pb [(size_t)(16 + g*4 + rr)*NN] = accA1[rr];
        pbB[(size_t)(g*4 + rr)*NN]      = accB0[rr];
        pbB[(size_t)(16 + g*4 + rr)*NN] = accB1[rr];
    }
    if (g == 0) { pb[(size_t)32*NN] = seA; pbB[(size_t)32*NN] = seB; }
}

// ---------------- K3: combine partials + output projection (o split 2-way) ----
__global__ __launch_bounds__(256) void kout(const float* __restrict__ part,
    const float* __restrict__ x, const float* __restrict__ wo,
    const float* __restrict__ bo, const float* __restrict__ gp,
    const float* __restrict__ wx, float* __restrict__ out)
{
    __shared__ float sw1[CC*CC], swx[CC*CC], sbo[CC];
    int blk = blockIdx.x;
    int b = blk >> 5;                   // 32 blocks per batch
    int n = (blk & 31)*128 + (threadIdx.x & 127);
    int oh = threadIdx.x >> 7;          // 0/1: output-channel half
    float g = gp[0];
    for (int i = threadIdx.x; i < CC*CC; i += 256) {
        int o = i >> 5, c2 = i & 31;
        sw1[i] = g * wo[o*64 + c2];
        swx[i] = wx[b*CC*CC + i];
    }
    if (threadIdx.x < CC) sbo[threadIdx.x] = bo[threadIdx.x];
    __syncthreads();

    const float* pb = part + (size_t)b*JG*33*NN + n;
    float acc[CC]; float se = 0.f;
    #pragma unroll
    for (int c = 0; c < CC; ++c) acc[c] = 0.f;
    #pragma unroll
    for (int jg = 0; jg < JG; ++jg) {
        const float* p = pb + (size_t)jg*33*NN;
        #pragma unroll
        for (int f = 0; f < CC; ++f) acc[f] += p[(size_t)f*NN];
        se += p[(size_t)32*NN];
    }
    float inv = 1.f/se;
    int ob0 = oh*16;
    float o_[16];
    #pragma unroll
    for (int o = 0; o < 16; ++o) o_[o] = sbo[ob0 + o];
    #pragma unroll
    for (int c = 0; c < CC; ++c) {
        float pc = acc[c]*inv;
        #pragma unroll
        for (int o = 0; o < 16; ++o) o_[o] += sw1[(ob0+o)*CC+c]*pc;
    }
    const float* xb = x + (size_t)b*CC*NN + n;
    #pragma unroll
    for (int d = 0; d < CC; ++d) {
        float xd = xb[(size_t)d*NN];
        #pragma unroll
        for (int o = 0; o < 16; ++o) o_[o] += swx[(ob0+o)*CC+d]*xd;
    }
    float* ob = out + (size_t)b*CC*NN + n;
    #pragma unroll
    for (int o = 0; o < 16; ++o) ob[(size_t)(ob0+o)*NN] = o_[o];
}

extern "C" void kernel_launch(void* const* d_in, const int* in_sizes, int n_in,
                              void* d_out, int out_size, void* d_ws, size_t ws_size,
                              hipStream_t stream)
{
    const float* x  = (const float*)d_in[0];
    const float* wq = (const float*)d_in[1];
    const float* bq = (const float*)d_in[2];
    const float* wk = (const float*)d_in[3];
    const float* bk = (const float*)d_in[4];
    const float* wv = (const float*)d_in[5];
    const float* bv = (const float*)d_in[6];
    const float* gp = (const float*)d_in[7];
    const float* gc = (const float*)d_in[8];
    const float* wo = (const float*)d_in[9];
    const float* bo = (const float*)d_in[10];

    float* ws   = (float*)d_ws;
    float* q    = ws;                  // B*C8*N = 32768 f
    float* k    = q + 32768;           // 32768 f
    short* vbf  = (short*)(k + 32768); // B*C*N = 262144 shorts = 131072 f
    float* eng  = k + 32768 + 131072;  // 2048 f
    float* wx   = eng + 2048;          // 2048 f
    float* part = wx + 2048;           // B*JG*33*N = 2162688 f (~9.6 MB total)

    k1<<<296, 256, 0, stream>>>(x, wq, bq, wk, bk, wv, bv, q, k, vbf, eng);
    k2<<<BB*32*JG + BB, 256, 0, stream>>>(q, k, vbf, part, eng, wo, gc, wx);
    kout<<<64, 256, 0, stream>>>(part, x, wo, bo, gp, wx, (float*)d_out);
}

// Round 6
// 43.970 us; speedup vs baseline: 1.0856x; 1.0856x over previous
//
#include <hip/hip_runtime.h>
#include <hip/hip_bf16.h>
#include <math.h>

#define BB 2
#define CC 32
#define C8 4
#define NN 4096
#define JG 8          // j-split groups
#define JR (NN/JG)    // 512 keys per flash block
#define LOG2E 1.4426950408889634f

typedef __attribute__((ext_vector_type(8))) short short8;
typedef __attribute__((ext_vector_type(4))) float f32x4;
typedef __attribute__((ext_vector_type(16))) float f32x16;
typedef __attribute__((ext_vector_type(4))) unsigned int u32x4;

static __device__ __forceinline__ short f2bf(float x) {
    return __builtin_bit_cast(short, __float2bfloat16(x));
}
// round-half-up bf16 pair pack: {bf16(b)|bf16(a)} (a low)
static __device__ __forceinline__ unsigned int pkbf(float a, float b) {
    unsigned int ua = __builtin_bit_cast(unsigned int, a) + 0x8000u;
    unsigned int ub = __builtin_bit_cast(unsigned int, b) + 0x8000u;
    return (ua >> 16) | (ub & 0xffff0000u);
}
static __device__ __forceinline__ short f2bfr(float a) {
    return (short)((__builtin_bit_cast(unsigned int, a) + 0x8000u) >> 16);
}
static __device__ __forceinline__ float bf2f(short s) {
    unsigned int u = ((unsigned int)(unsigned short)s) << 16;
    return __builtin_bit_cast(float, u);
}

// ---------------- K1: QKV projection (blocks 0..31) + CAM gram c<=d (blocks 32..295) ----
// qpk: bf16 [B][N][4] = q*LOG2E ; kpk: bf16 [B][N][4] ; vbf: bf16 [B][C][N]
__global__ __launch_bounds__(256) void k1(const float* __restrict__ x,
    const float* __restrict__ wq, const float* __restrict__ bq,
    const float* __restrict__ wk, const float* __restrict__ bk,
    const float* __restrict__ wv, const float* __restrict__ bv,
    short* __restrict__ qpk, short* __restrict__ kpk, short* __restrict__ vbf,
    float* __restrict__ eng)
{
    if (blockIdx.x >= 32) {
        // ---- keng: one wave per unordered pair (c<=d); 528 pairs per batch ----
        int w = threadIdx.x >> 6, lane = threadIdx.x & 63;
        int pp = (blockIdx.x - 32)*4 + w;     // 0..1055
        int b = pp >= 528 ? 1 : 0;
        int t = pp - b*528;
        int c = 0, rem = t;
        while (rem >= CC - c) { rem -= CC - c; ++c; }
        int d = c + rem;
        const float4* xc = (const float4*)(x + ((size_t)b*CC + c)*NN);
        const float4* xd = (const float4*)(x + ((size_t)b*CC + d)*NN);
        float s = 0.f;
        for (int tt = lane; tt < NN/4; tt += 64) {
            float4 a = xc[tt], bb = xd[tt];
            s += a.x*bb.x + a.y*bb.y + a.z*bb.z + a.w*bb.w;
        }
        #pragma unroll
        for (int off = 32; off; off >>= 1) s += __shfl_down(s, off, 64);
        if (lane == 0) {
            eng[(b*CC + c)*CC + d] = s;
            eng[(b*CC + d)*CC + c] = s;
        }
        return;
    }
    // ---- kproj: thread = (b,n) ----
    __shared__ float swq[C8*CC], swk[C8*CC], swv[CC*CC], sbq[C8], sbk[C8], sbv[CC];
    int tid = threadIdx.x;
    for (int i = tid; i < C8*CC; i += 256) { swq[i] = wq[i]; swk[i] = wk[i]; }
    for (int i = tid; i < CC*CC; i += 256) swv[i] = wv[i];
    if (tid < C8) { sbq[tid] = bq[tid]; sbk[tid] = bk[tid]; }
    if (tid < CC) sbv[tid] = bv[tid];
    __syncthreads();
    int g = blockIdx.x*256 + tid;         // 0..8191
    int b = g >> 12; int n = g & (NN-1);
    const float* xb = x + (size_t)b*CC*NN + n;
    float xr[CC];
    #pragma unroll
    for (int c = 0; c < CC; ++c) xr[c] = xb[(size_t)c*NN];
    float qv[C8], kv[C8];
    #pragma unroll
    for (int o = 0; o < C8; ++o) { qv[o] = sbq[o]; kv[o] = sbk[o]; }
    #pragma unroll
    for (int c = 0; c < CC; ++c) {
        float xc = xr[c];
        #pragma unroll
        for (int o = 0; o < C8; ++o) { qv[o] += swq[o*CC+c]*xc; kv[o] += swk[o*CC+c]*xc; }
    }
    short4 qs = make_short4(f2bf(qv[0]*LOG2E), f2bf(qv[1]*LOG2E),
                            f2bf(qv[2]*LOG2E), f2bf(qv[3]*LOG2E));
    short4 ks = make_short4(f2bf(kv[0]), f2bf(kv[1]), f2bf(kv[2]), f2bf(kv[3]));
    *(short4*)(qpk + ((size_t)b*NN + n)*4) = qs;
    *(short4*)(kpk + ((size_t)b*NN + n)*4) = ks;
    #pragma unroll
    for (int o = 0; o < CC; ++o) {
        float av = sbv[o];
        #pragma unroll
        for (int c = 0; c < CC; ++c) av += swv[o*CC+c]*xr[c];
        vbf[((size_t)b*CC+o)*NN + n] = f2bf(av);
    }
}

// ---------------- K2: flash PAM, dual-MFMA (blocks 0..511) + Wx fold (512..513) ----
// Wave = 32 queries x 512 keys. S = mfma_32x32x16(Kfrag, Qfrag): d=4 padded to 16.
// S D-layout: col q=lane&31, row k=(r&3)+8*(r>>2)+4*(lane>>5)  [measured m74/m101].
// PV key-order permuted to match: V fragment elems load cols k(t,h) -> no shuffles.
__global__ __launch_bounds__(256, 2) void k2(const short* __restrict__ qpk,
    const short* __restrict__ kpk, const short* __restrict__ vbf,
    short* __restrict__ ppart, float* __restrict__ sep,
    const float* __restrict__ eng, const float* __restrict__ wo,
    const float* __restrict__ gc, float* __restrict__ wx)
{
    if (blockIdx.x >= BB*32*JG) {
        // ---- kwx: CAM softmax folded into Wx, one block per batch ----
        __shared__ float se_[CC*CC], sc[CC*CC];
        int b = blockIdx.x - BB*32*JG, tid = threadIdx.x;
        for (int i = tid; i < CC*CC; i += 256) se_[i] = eng[b*CC*CC + i];
        __syncthreads();
        if (tid < CC) {
            float mn = se_[tid*CC];
            #pragma unroll
            for (int d = 1; d < CC; ++d) mn = fminf(mn, se_[tid*CC+d]);
            float pv[CC]; float s = 0.f;
            #pragma unroll
            for (int d = 0; d < CC; ++d) { pv[d] = __expf(mn - se_[tid*CC+d]); s += pv[d]; }
            float inv = 1.f/s;
            #pragma unroll
            for (int d = 0; d < CC; ++d) sc[tid*CC+d] = pv[d]*inv;
        }
        __syncthreads();
        float g = gc[0];
        for (int i = tid; i < CC*CC; i += 256) {
            int o = i >> 5, d = i & 31;
            float acc = wo[o*64 + d] + wo[o*64 + 32 + d];
            float t = 0.f;
            #pragma unroll
            for (int c2 = 0; c2 < CC; ++c2) t += wo[o*64 + 32 + c2] * sc[c2*CC + d];
            wx[b*CC*CC + i] = acc + g * t;
        }
        return;
    }

    int blk = blockIdx.x;
    int b = blk >> 8;            // 256 blocks per batch
    int r = blk & 255;
    int it = r >> 3;             // 0..31 (128 queries per block)
    int jg = r & (JG-1);         // 0..7
    int w = threadIdx.x >> 6, lane = threadIdx.x & 63;
    int qcol = lane & 31;
    int h = lane >> 5;
    int i0 = it*128 + w*32;
    int jbase = jg*JR;

    // Q fragment: B-operand, col=q, contraction elems t<4 (h==0) hold q*LOG2E
    short8 qf = {0,0,0,0,0,0,0,0};
    if (h == 0) {
        short4 qv = *(const short4*)(qpk + ((size_t)b*NN + i0 + qcol)*4);
        qf[0]=qv.x; qf[1]=qv.y; qf[2]=qv.z; qf[3]=qv.w;
    }
    const short* kp0  = kpk + ((size_t)b*NN + jbase + qcol)*4;     // A row k=lane&31
    const short* vrow = vbf + ((size_t)b*CC + qcol)*NN + jbase;    // A row c=lane&31

    f32x16 acc = {0,0,0,0,0,0,0,0,0,0,0,0,0,0,0,0};
    const f32x16 zz = {0,0,0,0,0,0,0,0,0,0,0,0,0,0,0,0};
    float se = 0.f;

    #pragma unroll 2
    for (int t = 0; t < JR/32; ++t) {
        int jb = t*32;
        short8 kf = {0,0,0,0,0,0,0,0};
        if (h == 0) {
            short4 kv = *(const short4*)(kp0 + (size_t)jb*4);
            kf[0]=kv.x; kf[1]=kv.y; kf[2]=kv.z; kf[3]=kv.w;
        }
        f32x16 s = __builtin_amdgcn_mfma_f32_32x32x16_bf16(kf, qf, zz, 0, 0, 0);
        float p[16];
        #pragma unroll
        for (int i = 0; i < 16; ++i) p[i] = exp2f(s[i]);
        float t0 = (p[0]+p[1])+(p[2]+p[3]), t1 = (p[4]+p[5])+(p[6]+p[7]);
        float t2 = (p[8]+p[9])+(p[10]+p[11]), t3 = (p[12]+p[13])+(p[14]+p[15]);
        se += (t0+t1)+(t2+t3);
        u32x4 u1, u2;
        u1[0]=pkbf(p[0],p[1]);   u1[1]=pkbf(p[2],p[3]);
        u1[2]=pkbf(p[4],p[5]);   u1[3]=pkbf(p[6],p[7]);
        u2[0]=pkbf(p[8],p[9]);   u2[1]=pkbf(p[10],p[11]);
        u2[2]=pkbf(p[12],p[13]); u2[3]=pkbf(p[14],p[15]);
        short8 pf1 = __builtin_bit_cast(short8, u1);
        short8 pf2 = __builtin_bit_cast(short8, u2);
        // V fragments at permuted key cols k(t,h) = (t&3)+8*(t>>2)+4h
        int vo = jb + 4*h;
        short4 va = *(const short4*)(vrow + vo);
        short4 vb4 = *(const short4*)(vrow + vo + 8);
        short4 vc = *(const short4*)(vrow + vo + 16);
        short4 vd = *(const short4*)(vrow + vo + 24);
        short8 vf1 = {va.x,va.y,va.z,va.w, vb4.x,vb4.y,vb4.z,vb4.w};
        short8 vf2 = {vc.x,vc.y,vc.z,vc.w, vd.x,vd.y,vd.z,vd.w};
        acc = __builtin_amdgcn_mfma_f32_32x32x16_bf16(vf1, pf1, acc, 0, 0, 0);
        acc = __builtin_amdgcn_mfma_f32_32x32x16_bf16(vf2, pf2, acc, 0, 0, 0);
    }

    se += __shfl_xor(se, 32, 64);   // combine the two key-halves per q

    // partials: ppart bf16 [b][jg][c][n], sep f32 [b][jg][n]
    short* pb = ppart + ((size_t)(b*JG + jg)*CC)*NN + i0 + qcol;
    #pragma unroll
    for (int rr = 0; rr < 16; ++rr) {
        int c = (rr&3) + 8*(rr>>2) + 4*h;
        pb[(size_t)c*NN] = f2bfr(acc[rr]);
    }
    if (h == 0) sep[((size_t)(b*JG + jg))*NN + i0 + qcol] = se;
}

// ---------------- K3: combine partials + output projection ----------------
__global__ __launch_bounds__(256) void kout(const short* __restrict__ ppart,
    const float* __restrict__ sep,
    const float* __restrict__ x, const float* __restrict__ wo,
    const float* __restrict__ bo, const float* __restrict__ gp,
    const float* __restrict__ wx, float* __restrict__ out)
{
    __shared__ float sw1[CC*CC], swx[CC*CC], sbo[CC];
    int blk = blockIdx.x;               // 128 blocks
    int b = blk >> 6;                   // 64 blocks per batch
    int n = (blk & 63)*64 + (threadIdx.x & 63);
    int oh = threadIdx.x >> 6;          // 0..3 output-channel quarter
    float g = gp[0];
    for (int i = threadIdx.x; i < CC*CC; i += 256) {
        int o = i >> 5, c2 = i & 31;
        sw1[i] = g * wo[o*64 + c2];
        swx[i] = wx[b*CC*CC + i];
    }
    if (threadIdx.x < CC) sbo[threadIdx.x] = bo[threadIdx.x];
    __syncthreads();

    const short* pb = ppart + (size_t)b*JG*CC*NN + n;
    const float* sb = sep + (size_t)b*JG*NN + n;
    float acc[CC]; float se = 0.f;
    #pragma unroll
    for (int c = 0; c < CC; ++c) acc[c] = 0.f;
    #pragma unroll
    for (int jg = 0; jg < JG; ++jg) {
        #pragma unroll
        for (int f = 0; f < CC; ++f) acc[f] += bf2f(pb[((size_t)jg*CC + f)*NN]);
        se += sb[(size_t)jg*NN];
    }
    float inv = 1.f/se;
    int ob0 = oh*8;
    float o_[8];
    #pragma unroll
    for (int o = 0; o < 8; ++o) o_[o] = sbo[ob0 + o];
    #pragma unroll
    for (int c = 0; c < CC; ++c) {
        float pc = acc[c]*inv;
        #pragma unroll
        for (int o = 0; o < 8; ++o) o_[o] += sw1[(ob0+o)*CC+c]*pc;
    }
    const float* xb = x + (size_t)b*CC*NN + n;
    #pragma unroll
    for (int d = 0; d < CC; ++d) {
        float xd = xb[(size_t)d*NN];
        #pragma unroll
        for (int o = 0; o < 8; ++o) o_[o] += swx[(ob0+o)*CC+d]*xd;
    }
    float* ob = out + (size_t)b*CC*NN + n;
    #pragma unroll
    for (int o = 0; o < 8; ++o) ob[(size_t)(ob0+o)*NN] = o_[o];
}

extern "C" void kernel_launch(void* const* d_in, const int* in_sizes, int n_in,
                              void* d_out, int out_size, void* d_ws, size_t ws_size,
                              hipStream_t stream)
{
    const float* x  = (const float*)d_in[0];
    const float* wq = (const float*)d_in[1];
    const float* bq = (const float*)d_in[2];
    const float* wk = (const float*)d_in[3];
    const float* bk = (const float*)d_in[4];
    const float* wv = (const float*)d_in[5];
    const float* bv = (const float*)d_in[6];
    const float* gp = (const float*)d_in[7];
    const float* gc = (const float*)d_in[8];
    const float* wo = (const float*)d_in[9];
    const float* bo = (const float*)d_in[10];

    short* qpk = (short*)d_ws;             // B*N*4   = 32768 sh
    short* kpk = qpk + 32768;              // 32768 sh
    short* vbf = kpk + 32768;              // B*C*N   = 262144 sh
    float* eng = (float*)(vbf + 262144);   // 2048 f
    float* wx  = eng + 2048;               // 2048 f
    float* sep = wx + 2048;                // B*JG*N  = 65536 f
    short* ppart = (short*)(sep + 65536);  // B*JG*C*N = 2097152 sh (~5 MB total)

    k1<<<296, 256, 0, stream>>>(x, wq, bq, wk, bk, wv, bv, qpk, kpk, vbf, eng);
    k2<<<BB*32*JG + BB, 256, 0, stream>>>(qpk, kpk, vbf, ppart, sep, eng, wo, gc, wx);
    kout<<<128, 256, 0, stream>>>(ppart, sep, x, wo, bo, gp, wx, (float*)d_out);
}

// Round 7
// 40.199 us; speedup vs baseline: 1.1874x; 1.0938x over previous
//
#include <hip/hip_runtime.h>
#include <hip/hip_bf16.h>
#include <math.h>

#define BB 2
#define CC 32
#define C8 4
#define NN 4096
#define JG 8          // j-split groups
#define JR (NN/JG)    // 512 keys per flash block
#define VSTRIDE 516   // LDS V row stride in shorts (8B-aligned rows, bank-rotated)
#define LOG2E 1.4426950408889634f

typedef __attribute__((ext_vector_type(8))) short short8;
typedef __attribute__((ext_vector_type(4))) float f32x4;
typedef __attribute__((ext_vector_type(16))) float f32x16;

static __device__ __forceinline__ short f2bf(float x) {
    return __builtin_bit_cast(short, __float2bfloat16(x));
}
// round-half-up bf16 pair pack: {bf16(b)|bf16(a)} (a low)
static __device__ __forceinline__ unsigned int pkbf(float a, float b) {
    unsigned int ua = __builtin_bit_cast(unsigned int, a) + 0x8000u;
    unsigned int ub = __builtin_bit_cast(unsigned int, b) + 0x8000u;
    return (ua >> 16) | (ub & 0xffff0000u);
}
static __device__ __forceinline__ short f2bfr(float a) {
    return (short)((__builtin_bit_cast(unsigned int, a) + 0x8000u) >> 16);
}
static __device__ __forceinline__ float bf2f(short s) {
    unsigned int u = ((unsigned int)(unsigned short)s) << 16;
    return __builtin_bit_cast(float, u);
}

// ---------------- K1: QKV projection (blocks 0..31) + CAM gram c<=d (blocks 32..295) ----
__global__ __launch_bounds__(256) void k1(const float* __restrict__ x,
    const float* __restrict__ wq, const float* __restrict__ bq,
    const float* __restrict__ wk, const float* __restrict__ bk,
    const float* __restrict__ wv, const float* __restrict__ bv,
    short* __restrict__ qpk, short* __restrict__ kpk, short* __restrict__ vbf,
    float* __restrict__ eng)
{
    if (blockIdx.x >= 32) {
        // ---- keng: one wave per unordered pair (c<=d); 528 pairs per batch ----
        int w = threadIdx.x >> 6, lane = threadIdx.x & 63;
        int pp = (blockIdx.x - 32)*4 + w;     // 0..1055
        int b = pp >= 528 ? 1 : 0;
        int t = pp - b*528;
        int c = 0, rem = t;
        while (rem >= CC - c) { rem -= CC - c; ++c; }
        int d = c + rem;
        const float4* xc = (const float4*)(x + ((size_t)b*CC + c)*NN);
        const float4* xd = (const float4*)(x + ((size_t)b*CC + d)*NN);
        float s = 0.f;
        for (int tt = lane; tt < NN/4; tt += 64) {
            float4 a = xc[tt], bb = xd[tt];
            s += a.x*bb.x + a.y*bb.y + a.z*bb.z + a.w*bb.w;
        }
        #pragma unroll
        for (int off = 32; off; off >>= 1) s += __shfl_down(s, off, 64);
        if (lane == 0) {
            eng[(b*CC + c)*CC + d] = s;
            eng[(b*CC + d)*CC + c] = s;
        }
        return;
    }
    // ---- kproj: thread = (b,n) ----
    __shared__ float swq[C8*CC], swk[C8*CC], swv[CC*CC], sbq[C8], sbk[C8], sbv[CC];
    int tid = threadIdx.x;
    for (int i = tid; i < C8*CC; i += 256) { swq[i] = wq[i]; swk[i] = wk[i]; }
    for (int i = tid; i < CC*CC; i += 256) swv[i] = wv[i];
    if (tid < C8) { sbq[tid] = bq[tid]; sbk[tid] = bk[tid]; }
    if (tid < CC) sbv[tid] = bv[tid];
    __syncthreads();
    int g = blockIdx.x*256 + tid;         // 0..8191
    int b = g >> 12; int n = g & (NN-1);
    const float* xb = x + (size_t)b*CC*NN + n;
    float xr[CC];
    #pragma unroll
    for (int c = 0; c < CC; ++c) xr[c] = xb[(size_t)c*NN];
    float qv[C8], kv[C8];
    #pragma unroll
    for (int o = 0; o < C8; ++o) { qv[o] = sbq[o]; kv[o] = sbk[o]; }
    #pragma unroll
    for (int c = 0; c < CC; ++c) {
        float xc = xr[c];
        #pragma unroll
        for (int o = 0; o < C8; ++o) { qv[o] += swq[o*CC+c]*xc; kv[o] += swk[o*CC+c]*xc; }
    }
    short4 qs = make_short4(f2bf(qv[0]*LOG2E), f2bf(qv[1]*LOG2E),
                            f2bf(qv[2]*LOG2E), f2bf(qv[3]*LOG2E));
    short4 ks = make_short4(f2bf(kv[0]), f2bf(kv[1]), f2bf(kv[2]), f2bf(kv[3]));
    *(short4*)(qpk + ((size_t)b*NN + n)*4) = qs;
    *(short4*)(kpk + ((size_t)b*NN + n)*4) = ks;
    #pragma unroll
    for (int o = 0; o < CC; ++o) {
        float av = sbv[o];
        #pragma unroll
        for (int c = 0; c < CC; ++c) av += swv[o*CC+c]*xr[c];
        vbf[((size_t)b*CC+o)*NN + n] = f2bf(av);
    }
}

// ---------------- K2: flash PAM, dual-MFMA, V in LDS (blocks 0..511) + Wx fold (512..513) ----
// Wave = 32 queries x 512 keys. S = mfma_32x32x16(Kfrag, Qfrag), d=4 zero-padded.
// S D-layout: col q=lane&31, row k=(r&3)+8*(r>>2)+4*(lane>>5). PV key-order permuted to
// match; V served from a 32KB LDS slab shared by all 4 waves (conflict-lite ds_read_b64).
// Register-lean body, #pragma unroll 1: must fit the 128-VGPR cap of launch_bounds(256,2).
__global__ __launch_bounds__(256, 2) void k2(const short* __restrict__ qpk,
    const short* __restrict__ kpk, const short* __restrict__ vbf,
    short* __restrict__ ppart, float* __restrict__ sep,
    const float* __restrict__ eng, const float* __restrict__ wo,
    const float* __restrict__ gc, float* __restrict__ wx)
{
    __shared__ __align__(16) char smem[CC*VSTRIDE*2];   // 33 KB, aliased by both paths

    if (blockIdx.x >= BB*32*JG) {
        // ---- kwx: CAM softmax folded into Wx, one block per batch ----
        float* se_ = (float*)smem;                // [CC*CC]
        float* sc  = (float*)(smem + CC*CC*4);    // [CC*CC]
        int b = blockIdx.x - BB*32*JG, tid = threadIdx.x;
        for (int i = tid; i < CC*CC; i += 256) se_[i] = eng[b*CC*CC + i];
        __syncthreads();
        if (tid < CC) {
            float mn = se_[tid*CC];
            #pragma unroll
            for (int d = 1; d < CC; ++d) mn = fminf(mn, se_[tid*CC+d]);
            float pv[CC]; float s = 0.f;
            #pragma unroll
            for (int d = 0; d < CC; ++d) { pv[d] = __expf(mn - se_[tid*CC+d]); s += pv[d]; }
            float inv = 1.f/s;
            #pragma unroll
            for (int d = 0; d < CC; ++d) sc[tid*CC+d] = pv[d]*inv;
        }
        __syncthreads();
        float g = gc[0];
        for (int i = tid; i < CC*CC; i += 256) {
            int o = i >> 5, d = i & 31;
            float acc = wo[o*64 + d] + wo[o*64 + 32 + d];
            float t = 0.f;
            #pragma unroll
            for (int c2 = 0; c2 < CC; ++c2) t += wo[o*64 + 32 + c2] * sc[c2*CC + d];
            wx[b*CC*CC + i] = acc + g * t;
        }
        return;
    }

    int blk = blockIdx.x;
    int b = blk >> 8;            // 256 blocks per batch
    int r = blk & 255;
    int it = r >> 3;             // 0..31 (128 queries per block)
    int jg = r & (JG-1);         // 0..7
    int jbase = jg*JR;
    int tid = threadIdx.x;

    // ---- stage V slab [32 rows][512 keys] -> LDS, row stride VSTRIDE ----
    short* vsl = (short*)smem;
    {
        const short* vgp = vbf + (size_t)b*CC*NN + jbase;
        #pragma unroll
        for (int i2 = 0; i2 < 16; ++i2) {
            int idx = tid + i2*256;          // 0..4095 short4 granules
            int rr2 = idx >> 7;              // row 0..31 (128 granules/row)
            int cg  = idx & 127;
            *(short4*)(vsl + rr2*VSTRIDE + cg*4) =
                *(const short4*)(vgp + (size_t)rr2*NN + cg*4);
        }
    }
    __syncthreads();

    int w = tid >> 6, lane = tid & 63;
    int qcol = lane & 31;
    int h = lane >> 5;
    int i0 = it*128 + w*32;

    // Q fragment: B-operand, col=q, contraction elems t<4 (h==0) hold q*LOG2E
    short8 qf = {0,0,0,0,0,0,0,0};
    if (h == 0) {
        short4 qv = *(const short4*)(qpk + ((size_t)b*NN + i0 + qcol)*4);
        qf[0]=qv.x; qf[1]=qv.y; qf[2]=qv.z; qf[3]=qv.w;
    }
    const short* kp0  = kpk + ((size_t)b*NN + jbase + qcol)*4;   // A row k=lane&31
    const short* vrow = vsl + qcol*VSTRIDE;                      // A row c=lane&31

    f32x16 acc = {0,0,0,0,0,0,0,0,0,0,0,0,0,0,0,0};
    const f32x16 zz = {0,0,0,0,0,0,0,0,0,0,0,0,0,0,0,0};
    float se = 0.f;

    #pragma unroll 1
    for (int t = 0; t < JR/32; ++t) {
        int jb = t*32;
        short8 kf = {0,0,0,0,0,0,0,0};
        if (h == 0) {
            short4 kv = *(const short4*)(kp0 + (size_t)jb*4);
            kf[0]=kv.x; kf[1]=kv.y; kf[2]=kv.z; kf[3]=kv.w;
        }
        f32x16 s = __builtin_amdgcn_mfma_f32_32x32x16_bf16(kf, qf, zz, 0, 0, 0);
        // exp in place, sum, pack (transients consumed immediately)
        #pragma unroll
        for (int i = 0; i < 16; ++i) s[i] = exp2f(s[i]);
        se += (((s[0]+s[1])+(s[2]+s[3])) + ((s[4]+s[5])+(s[6]+s[7])))
            + (((s[8]+s[9])+(s[10]+s[11])) + ((s[12]+s[13])+(s[14]+s[15])));
        unsigned int u0 = pkbf(s[0],s[1]),   u1 = pkbf(s[2],s[3]);
        unsigned int u2 = pkbf(s[4],s[5]),   u3 = pkbf(s[6],s[7]);
        unsigned int u4 = pkbf(s[8],s[9]),   u5 = pkbf(s[10],s[11]);
        unsigned int u6 = pkbf(s[12],s[13]), u7 = pkbf(s[14],s[15]);
        // V fragments from LDS at permuted key cols (vo=jb+4h, +8, +16, +24)
        int vo = jb + 4*h;
        short4 a0 = *(const short4*)(vrow + vo);
        short4 a1 = *(const short4*)(vrow + vo + 8);
        short4 a2 = *(const short4*)(vrow + vo + 16);
        short4 a3 = *(const short4*)(vrow + vo + 24);
        short8 vf1 = {a0.x,a0.y,a0.z,a0.w, a1.x,a1.y,a1.z,a1.w};
        short8 pf1 = {(short)u0,(short)(u0>>16),(short)u1,(short)(u1>>16),
                      (short)u2,(short)(u2>>16),(short)u3,(short)(u3>>16)};
        acc = __builtin_amdgcn_mfma_f32_32x32x16_bf16(vf1, pf1, acc, 0, 0, 0);
        short8 vf2 = {a2.x,a2.y,a2.z,a2.w, a3.x,a3.y,a3.z,a3.w};
        short8 pf2 = {(short)u4,(short)(u4>>16),(short)u5,(short)(u5>>16),
                      (short)u6,(short)(u6>>16),(short)u7,(short)(u7>>16)};
        acc = __builtin_amdgcn_mfma_f32_32x32x16_bf16(vf2, pf2, acc, 0, 0, 0);
    }

    se += __shfl_xor(se, 32, 64);   // combine the two key-halves per q

    // partials: ppart bf16 [b][jg][c][n], sep f32 [b][jg][n]
    short* pb = ppart + ((size_t)(b*JG + jg)*CC)*NN + i0 + qcol;
    #pragma unroll
    for (int rr = 0; rr < 16; ++rr) {
        int c = (rr&3) + 8*(rr>>2) + 4*h;
        pb[(size_t)c*NN] = f2bfr(acc[rr]);
    }
    if (h == 0) sep[((size_t)(b*JG + jg))*NN + i0 + qcol] = se;
}

// ---------------- K3: combine partials + output projection ----------------
__global__ __launch_bounds__(256) void kout(const short* __restrict__ ppart,
    const float* __restrict__ sep,
    const float* __restrict__ x, const float* __restrict__ wo,
    const float* __restrict__ bo, const float* __restrict__ gp,
    const float* __restrict__ wx, float* __restrict__ out)
{
    __shared__ float sw1[CC*CC], swx[CC*CC], sbo[CC];
    int blk = blockIdx.x;               // 128 blocks
    int b = blk >> 6;                   // 64 blocks per batch
    int n = (blk & 63)*64 + (threadIdx.x & 63);
    int oh = threadIdx.x >> 6;          // 0..3 output-channel quarter
    float g = gp[0];
    for (int i = threadIdx.x; i < CC*CC; i += 256) {
        int o = i >> 5, c2 = i & 31;
        sw1[i] = g * wo[o*64 + c2];
        swx[i] = wx[b*CC*CC + i];
    }
    if (threadIdx.x < CC) sbo[threadIdx.x] = bo[threadIdx.x];
    __syncthreads();

    const short* pb = ppart + (size_t)b*JG*CC*NN + n;
    const float* sb = sep + (size_t)b*JG*NN + n;
    float acc[CC]; float se = 0.f;
    #pragma unroll
    for (int c = 0; c < CC; ++c) acc[c] = 0.f;
    #pragma unroll
    for (int jg = 0; jg < JG; ++jg) {
        #pragma unroll
        for (int f = 0; f < CC; ++f) acc[f] += bf2f(pb[((size_t)jg*CC + f)*NN]);
        se += sb[(size_t)jg*NN];
    }
    float inv = 1.f/se;
    int ob0 = oh*8;
    float o_[8];
    #pragma unroll
    for (int o = 0; o < 8; ++o) o_[o] = sbo[ob0 + o];
    #pragma unroll
    for (int c = 0; c < CC; ++c) {
        float pc = acc[c]*inv;
        #pragma unroll
        for (int o = 0; o < 8; ++o) o_[o] += sw1[(ob0+o)*CC+c]*pc;
    }
    const float* xb = x + (size_t)b*CC*NN + n;
    #pragma unroll
    for (int d = 0; d < CC; ++d) {
        float xd = xb[(size_t)d*NN];
        #pragma unroll
        for (int o = 0; o < 8; ++o) o_[o] += swx[(ob0+o)*CC+d]*xd;
    }
    float* ob = out + (size_t)b*CC*NN + n;
    #pragma unroll
    for (int o = 0; o < 8; ++o) ob[(size_t)(ob0+o)*NN] = o_[o];
}

extern "C" void kernel_launch(void* const* d_in, const int* in_sizes, int n_in,
                              void* d_out, int out_size, void* d_ws, size_t ws_size,
                              hipStream_t stream)
{
    const float* x  = (const float*)d_in[0];
    const float* wq = (const float*)d_in[1];
    const float* bq = (const float*)d_in[2];
    const float* wk = (const float*)d_in[3];
    const float* bk = (const float*)d_in[4];
    const float* wv = (const float*)d_in[5];
    const float* bv = (const float*)d_in[6];
    const float* gp = (const float*)d_in[7];
    const float* gc = (const float*)d_in[8];
    const float* wo = (const float*)d_in[9];
    const float* bo = (const float*)d_in[10];

    short* qpk = (short*)d_ws;             // B*N*4   = 32768 sh
    short* kpk = qpk + 32768;              // 32768 sh
    short* vbf = kpk + 32768;              // B*C*N   = 262144 sh
    float* eng = (float*)(vbf + 262144);   // 2048 f
    float* wx  = eng + 2048;               // 2048 f
    float* sep = wx + 2048;                // B*JG*N  = 65536 f
    short* ppart = (short*)(sep + 65536);  // B*JG*C*N = 2097152 sh (~5 MB total)

    k1<<<296, 256, 0, stream>>>(x, wq, bq, wk, bk, wv, bv, qpk, kpk, vbf, eng);
    k2<<<BB*32*JG + BB, 256, 0, stream>>>(qpk, kpk, vbf, ppart, sep, eng, wo, gc, wx);
    kout<<<128, 256, 0, stream>>>(ppart, sep, x, wo, bo, gp, wx, (float*)d_out);
}